// Round 1
// baseline (4290.166 us; speedup 1.0000x reference)
//
#include <hip/hip_runtime.h>
#include <math.h>

#define NN 100000
#define EE 1600000
#define CC 20
#define DD 8
#define GG 1024
#define LL 2
#define KK (2*CC+DD)   // 48
#define EPSV 1e-5f

// ---------------- edge message + scatter-add ----------------
// One thread per edge. Weights for this layer staged in LDS (broadcast reads).
// z[48] and both accumulators fully unrolled -> registers.
__global__ __launch_bounds__(256) void k_edge(
    const float* __restrict__ x, const int* __restrict__ ei,
    const float* __restrict__ ea,
    const float* __restrict__ wf, const float* __restrict__ bf,
    const float* __restrict__ wsm, const float* __restrict__ bs,
    float* __restrict__ y)
{
    __shared__ float sWf[KK * CC];
    __shared__ float sWs[KK * CC];
    __shared__ float sBf[CC];
    __shared__ float sBs[CC];
    for (int i = threadIdx.x; i < KK * CC; i += 256) {
        sWf[i] = wf[i];
        sWs[i] = wsm[i];
    }
    if (threadIdx.x < CC) {
        sBf[threadIdx.x] = bf[threadIdx.x];
        sBs[threadIdx.x] = bs[threadIdx.x];
    }
    __syncthreads();

    int e = blockIdx.x * 256 + threadIdx.x;
    if (e >= EE) return;

    int s = ei[e];        // x_j (source)
    int d = ei[EE + e];   // x_i (target)

    float z[KK];
    const float4* xd = reinterpret_cast<const float4*>(x + (size_t)d * CC);
    const float4* xs = reinterpret_cast<const float4*>(x + (size_t)s * CC);
    const float4* ep = reinterpret_cast<const float4*>(ea + (size_t)e * DD);
#pragma unroll
    for (int q = 0; q < 5; ++q) {
        float4 v = xd[q];
        z[4*q+0] = v.x; z[4*q+1] = v.y; z[4*q+2] = v.z; z[4*q+3] = v.w;
    }
#pragma unroll
    for (int q = 0; q < 5; ++q) {
        float4 v = xs[q];
        z[CC+4*q+0] = v.x; z[CC+4*q+1] = v.y; z[CC+4*q+2] = v.z; z[CC+4*q+3] = v.w;
    }
#pragma unroll
    for (int q = 0; q < 2; ++q) {
        float4 v = ep[q];
        z[2*CC+4*q+0] = v.x; z[2*CC+4*q+1] = v.y; z[2*CC+4*q+2] = v.z; z[2*CC+4*q+3] = v.w;
    }

    float f[CC], g[CC];
#pragma unroll
    for (int c = 0; c < CC; ++c) { f[c] = sBf[c]; g[c] = sBs[c]; }
#pragma unroll
    for (int k = 0; k < KK; ++k) {
        float zk = z[k];
#pragma unroll
        for (int c = 0; c < CC; ++c) {
            f[c] = fmaf(zk, sWf[k*CC + c], f[c]);
            g[c] = fmaf(zk, sWs[k*CC + c], g[c]);
        }
    }

    float* yd = y + (size_t)d * CC;
#pragma unroll
    for (int c = 0; c < CC; ++c) {
        float sg = 1.0f / (1.0f + __expf(-f[c]));
        float sp = fmaxf(g[c], 0.0f) + log1pf(__expf(-fabsf(g[c])));
        atomicAdd(yd + c, sg * sp);
    }
}

// ---------------- BN stats: per-channel sum and sumsq ----------------
__global__ __launch_bounds__(256) void k_bnstats(const float* __restrict__ y,
                                                 float* __restrict__ sums)
{
    int n = blockIdx.x * 256 + threadIdx.x;
    float v[CC];
    if (n < NN) {
        const float4* p = reinterpret_cast<const float4*>(y + (size_t)n * CC);
#pragma unroll
        for (int q = 0; q < 5; ++q) {
            float4 t = p[q];
            v[4*q+0] = t.x; v[4*q+1] = t.y; v[4*q+2] = t.z; v[4*q+3] = t.w;
        }
    } else {
#pragma unroll
        for (int c = 0; c < CC; ++c) v[c] = 0.0f;
    }
    int lane = threadIdx.x & 63;
#pragma unroll
    for (int c = 0; c < CC; ++c) {
        float a = v[c];
        float b = a * a;
        for (int o = 32; o > 0; o >>= 1) {
            a += __shfl_down(a, o);
            b += __shfl_down(b, o);
        }
        if (lane == 0) {
            atomicAdd(&sums[c], a);
            atomicAdd(&sums[CC + c], b);
        }
    }
}

// ---------------- BN apply + tanh (in place) ----------------
__global__ __launch_bounds__(256) void k_bnapply(float* __restrict__ y,
                                                 const float* __restrict__ sums,
                                                 const float* __restrict__ gam,
                                                 const float* __restrict__ bet)
{
    int n = blockIdx.x * 256 + threadIdx.x;
    if (n >= NN) return;
    const float inv = 1.0f / (float)NN;
    float4* p = reinterpret_cast<float4*>(y + (size_t)n * CC);
    float v[CC];
#pragma unroll
    for (int q = 0; q < 5; ++q) {
        float4 t = p[q];
        v[4*q+0] = t.x; v[4*q+1] = t.y; v[4*q+2] = t.z; v[4*q+3] = t.w;
    }
#pragma unroll
    for (int c = 0; c < CC; ++c) {
        float mean = sums[c] * inv;
        float var  = sums[CC + c] * inv - mean * mean;
        float scale = gam[c] * rsqrtf(var + EPSV);
        float shift = bet[c] - mean * scale;
        v[c] = tanhf(fmaf(v[c], scale, shift));
    }
#pragma unroll
    for (int q = 0; q < 5; ++q) {
        p[q] = make_float4(v[4*q+0], v[4*q+1], v[4*q+2], v[4*q+3]);
    }
}

// ---------------- global add pool ----------------
__global__ __launch_bounds__(256) void k_pool(const float* __restrict__ x,
                                              const int* __restrict__ batch,
                                              float* __restrict__ pooled)
{
    int n = blockIdx.x * 256 + threadIdx.x;
    int nc = n < NN ? n : NN - 1;
    bool valid = n < NN;
    int g = batch[nc];
    float v[CC];
    {
        const float4* p = reinterpret_cast<const float4*>(x + (size_t)nc * CC);
#pragma unroll
        for (int q = 0; q < 5; ++q) {
            float4 t = p[q];
            v[4*q+0] = t.x; v[4*q+1] = t.y; v[4*q+2] = t.z; v[4*q+3] = t.w;
        }
        if (!valid) {
#pragma unroll
            for (int c = 0; c < CC; ++c) v[c] = 0.0f;
        }
    }
    int lane = threadIdx.x & 63;
    int g0 = __shfl(g, 0);
    if (__all(g == g0)) {
#pragma unroll
        for (int c = 0; c < CC; ++c) {
            float a = v[c];
            for (int o = 32; o > 0; o >>= 1) a += __shfl_down(a, o);
            if (lane == 0) atomicAdd(&pooled[(size_t)g0 * CC + c], a);
        }
    } else if (valid) {
#pragma unroll
        for (int c = 0; c < CC; ++c) atomicAdd(&pooled[(size_t)g * CC + c], v[c]);
    }
}

// ---------------- final MLP ----------------
__global__ __launch_bounds__(256) void k_mlp(const float* __restrict__ pooled,
    const float* __restrict__ w1, const float* __restrict__ b1,
    const float* __restrict__ w2, const float* __restrict__ b2,
    const float* __restrict__ w3, const float* __restrict__ b3,
    float* __restrict__ out)
{
    __shared__ float sw1[CC * 32];
    __shared__ float sb1[32];
    __shared__ float sw2[32 * 8];
    __shared__ float sb2[8];
    __shared__ float sw3[8];
    for (int i = threadIdx.x; i < CC * 32; i += 256) sw1[i] = w1[i];
    if (threadIdx.x < 32) sb1[threadIdx.x] = b1[threadIdx.x];
    for (int i = threadIdx.x; i < 32 * 8; i += 256) sw2[i] = w2[i];
    if (threadIdx.x < 8) { sb2[threadIdx.x] = b2[threadIdx.x]; sw3[threadIdx.x] = w3[threadIdx.x]; }
    __syncthreads();

    int gi = blockIdx.x * 256 + threadIdx.x;
    if (gi >= GG) return;

    float p[CC];
    const float4* pp = reinterpret_cast<const float4*>(pooled + (size_t)gi * CC);
#pragma unroll
    for (int q = 0; q < 5; ++q) {
        float4 t = pp[q];
        p[4*q+0] = t.x; p[4*q+1] = t.y; p[4*q+2] = t.z; p[4*q+3] = t.w;
    }
    float h1[32];
#pragma unroll
    for (int j = 0; j < 32; ++j) h1[j] = sb1[j];
#pragma unroll
    for (int c = 0; c < CC; ++c) {
        float pc = p[c];
#pragma unroll
        for (int j = 0; j < 32; ++j) h1[j] = fmaf(pc, sw1[c*32 + j], h1[j]);
    }
#pragma unroll
    for (int j = 0; j < 32; ++j) h1[j] = tanhf(h1[j]);
    float h2[8];
#pragma unroll
    for (int j = 0; j < 8; ++j) h2[j] = sb2[j];
#pragma unroll
    for (int c = 0; c < 32; ++c) {
        float hc = h1[c];
#pragma unroll
        for (int j = 0; j < 8; ++j) h2[j] = fmaf(hc, sw2[c*8 + j], h2[j]);
    }
    float o = b3[0];
#pragma unroll
    for (int j = 0; j < 8; ++j) o = fmaf(tanhf(h2[j]), sw3[j], o);
    out[gi] = o;
}

extern "C" void kernel_launch(void* const* d_in, const int* in_sizes, int n_in,
                              void* d_out, int out_size, void* d_ws, size_t ws_size,
                              hipStream_t stream) {
    const float* x   = (const float*)d_in[0];
    const int*   ei  = (const int*)d_in[1];
    const float* ea  = (const float*)d_in[2];
    const int*   bat = (const int*)d_in[3];
    const float* lfw = (const float*)d_in[4];
    const float* lfb = (const float*)d_in[5];
    const float* lsw = (const float*)d_in[6];
    const float* lsb = (const float*)d_in[7];
    const float* bng = (const float*)d_in[8];
    const float* bnb = (const float*)d_in[9];
    const float* w1  = (const float*)d_in[10];
    const float* b1  = (const float*)d_in[11];
    const float* w2  = (const float*)d_in[12];
    const float* b2  = (const float*)d_in[13];
    const float* w3  = (const float*)d_in[14];
    const float* b3  = (const float*)d_in[15];
    float* out = (float*)d_out;

    char* ws = (char*)d_ws;
    const size_t rowBytes = (size_t)NN * CC * sizeof(float); // 8 MB
    float* A      = (float*)(ws);
    float* B      = (float*)(ws + rowBytes);
    float* sums   = (float*)(ws + 2 * rowBytes);
    float* pooled = (float*)(ws + 2 * rowBytes + 256);

    const float* xcur = x;
    for (int l = 0; l < LL; ++l) {
        float* y = (l == 0) ? A : B;
        hipMemcpyAsync(y, xcur, rowBytes, hipMemcpyDeviceToDevice, stream);
        k_edge<<<(EE + 255) / 256, 256, 0, stream>>>(
            xcur, ei, ea,
            lfw + (size_t)l * KK * CC, lfb + (size_t)l * CC,
            lsw + (size_t)l * KK * CC, lsb + (size_t)l * CC, y);
        hipMemsetAsync(sums, 0, 2 * CC * sizeof(float), stream);
        k_bnstats<<<(NN + 255) / 256, 256, 0, stream>>>(y, sums);
        k_bnapply<<<(NN + 255) / 256, 256, 0, stream>>>(y, sums,
            bng + (size_t)l * CC, bnb + (size_t)l * CC);
        xcur = y;
    }
    hipMemsetAsync(pooled, 0, (size_t)GG * CC * sizeof(float), stream);
    k_pool<<<(NN + 255) / 256, 256, 0, stream>>>(xcur, bat, pooled);
    k_mlp<<<(GG + 255) / 256, 256, 0, stream>>>(pooled, w1, b1, w2, b2, w3, b3, out);
}